// Round 1
// 4179.990 us; speedup vs baseline: 1.0194x; 1.0194x over previous
//
#include <hip/hip_runtime.h>
#include <hip/hip_fp16.h>

#define H 161
#define G4 644            // 4*H gates
#define BB 32             // batch
#define TT 1000           // time
#define M_TOT (BB*TT)     // 32000 rows
#define NPAIR 84          // half2 pairs covering K padded to 168
#define NVEC (NPAIR/4)    // 21 uint4 reads of the h vector

typedef _Float16 h2_t __attribute__((ext_vector_type(2)));

__device__ __forceinline__ h2_t bc_h2(unsigned int u) {
    return __builtin_bit_cast(h2_t, u);
}

__device__ __forceinline__ float dot2f(h2_t a, h2_t b, float c) {
#if __has_builtin(__builtin_amdgcn_fdot2)
    return __builtin_amdgcn_fdot2(a, b, c, false);
#else
    return c + (float)a[0] * (float)b[0] + (float)a[1] * (float)b[1];
#endif
}

__device__ __forceinline__ float sigm_f(float x) {
    return 1.0f / (1.0f + __expf(-x));
}
__device__ __forceinline__ float tanh_f(float x) {
    // 1 - 2/(e^{2x}+1); saturates correctly at +-inf without NaN
    return 1.0f - 2.0f / (__expf(2.0f * x) + 1.0f);
}

// Raw workgroup barrier that only drains LDS (lgkmcnt), NOT vmcnt.
// __syncthreads() would force s_waitcnt vmcnt(0) and stall on the hcat
// store ack + kill the pre-load prefetch every step. Data crosses these
// barriers only through LDS, so lgkmcnt(0) is sufficient.
// sched_barrier(0) + "memory" clobber fence compiler reordering (rule #18).
__device__ __forceinline__ void bar_lds() {
    __builtin_amdgcn_sched_barrier(0);
    asm volatile("s_waitcnt lgkmcnt(0)" ::: "memory");
    __builtin_amdgcn_s_barrier();
    __builtin_amdgcn_sched_barrier(0);
}

// ---------------------------------------------------------------------------
// pre_gemm: pre[d][m][g] = sum_k A[m][k] * wih_d[g][k] + bih_d[g] + bhh_d[g]
// A: [M_TOT][H] fp32. Output half [2][M_TOT][G4].
// Tiles: BM=64, BN=64, BK=16. 256 threads, 4x4 per thread.
// ---------------------------------------------------------------------------
__global__ __launch_bounds__(256) void pre_gemm(
    const float* __restrict__ A,
    const float* __restrict__ wf, const float* __restrict__ wb,
    const float* __restrict__ bif, const float* __restrict__ bhf,
    const float* __restrict__ bib, const float* __restrict__ bhb,
    __half* __restrict__ pre)
{
    const int BM = 64, BN = 64, BK = 16;
    int m0 = blockIdx.x * BM;
    int n0 = blockIdx.y * BN;           // n in [0, 1288) padded to 1344
    __shared__ float As[BK][BM + 1];
    __shared__ float Bs[BK][BN + 1];
    int tid = threadIdx.x;
    int tx = tid & 15, ty = tid >> 4;
    float acc[4][4] = {};

    for (int k0 = 0; k0 < H; k0 += BK) {
        #pragma unroll
        for (int l = 0; l < (BM * BK) / 256; ++l) {
            int e = tid + l * 256;
            int mm = e / BK, kk = e % BK;
            int k = k0 + kk;
            As[kk][mm] = (k < H) ? A[(size_t)(m0 + mm) * H + k] : 0.f;
        }
        #pragma unroll
        for (int l = 0; l < (BN * BK) / 256; ++l) {
            int e = tid + l * 256;
            int nn = e / BK, kk = e % BK;
            int n = n0 + nn, k = k0 + kk;
            float v = 0.f;
            if (k < H && n < 2 * G4)
                v = (n < G4) ? wf[(size_t)n * H + k] : wb[(size_t)(n - G4) * H + k];
            Bs[kk][nn] = v;
        }
        __syncthreads();
        #pragma unroll
        for (int kk = 0; kk < BK; ++kk) {
            float a4[4], b4[4];
            #pragma unroll
            for (int i = 0; i < 4; ++i) a4[i] = As[kk][ty + 16 * i];
            #pragma unroll
            for (int j = 0; j < 4; ++j) b4[j] = Bs[kk][tx + 16 * j];
            #pragma unroll
            for (int i = 0; i < 4; ++i)
                #pragma unroll
                for (int j = 0; j < 4; ++j) acc[i][j] += a4[i] * b4[j];
        }
        __syncthreads();
    }

    #pragma unroll
    for (int i = 0; i < 4; ++i) {
        int m = m0 + ty + 16 * i;
        #pragma unroll
        for (int j = 0; j < 4; ++j) {
            int n = n0 + tx + 16 * j;
            if (n < 2 * G4) {
                int d = (n >= G4) ? 1 : 0;
                int g = n - d * G4;
                float bias = d ? (bib[g] + bhb[g]) : (bif[g] + bhf[g]);
                pre[((size_t)d * M_TOT + m) * G4 + g] = __float2half(acc[i][j] + bias);
            }
        }
    }
}

// ---------------------------------------------------------------------------
// lstm_scan: one block per (batch, direction). 704 threads; thread g < 644
// owns gate g with its whh row held in VGPRs as 84 packed half2.
// h kept in LDS as f16 (padded to 168), c kept in registers of threads < H.
//
// launch_bounds(704, 3): min 3 waves/EU -> VGPR cap 170. Without this the
// compiler capped at 80 arch VGPRs and the 84-reg w[] array could not live
// in arch VGPRs (AGPR/scratch round-trips every step).
// ---------------------------------------------------------------------------
__global__ __launch_bounds__(704, 3) void lstm_scan(
    const __half* __restrict__ pre,      // [2][M_TOT][G4]
    const float* __restrict__ whh_f,
    const float* __restrict__ whh_b,
    float* __restrict__ hcat)            // [M_TOT][2*H]
{
    const int b = blockIdx.x;            // 0..31
    const int d = blockIdx.y;            // 0,1
    const int tid = threadIdx.x;
    const float* whh = d ? whh_b : whh_f;

    __shared__ __align__(16) unsigned int h_sh[NPAIR];  // 168 halves
    __shared__ float gate_sh[G4];

    const bool active = tid < G4;
    h2_t w[NPAIR];
    if (active) {
        const float* row = whh + (size_t)tid * H;
        #pragma unroll
        for (int i = 0; i < NPAIR; ++i) {
            float w0 = (2 * i < H) ? row[2 * i] : 0.f;
            float w1 = (2 * i + 1 < H) ? row[2 * i + 1] : 0.f;
            h2_t v; v[0] = (_Float16)w0; v[1] = (_Float16)w1;
            w[i] = v;
        }
    }
    if (tid < NPAIR) h_sh[tid] = 0u;
    float c = 0.f;
    const __half* pb = pre + ((size_t)d * M_TOT + (size_t)b * TT) * G4;
    const bool is_g_gate = (tid >= 2 * H) && (tid < 3 * H);

    // Prefetch pre for the first step.
    int t0 = d ? (TT - 1) : 0;
    __half pc = __half(0.0f);
    if (active) pc = pb[(long long)t0 * G4 + tid];
    __syncthreads();

    for (int ttt = 0; ttt < TT; ++ttt) {
        int t = d ? (TT - 1 - ttt) : ttt;
        // Prefetch next step's pre one full step ahead. Unclamped t+-1 stays
        // inside the [2][M_TOT][G4] buffer for every (b,d) (verified), and the
        // final iteration's stale prefetch is never consumed.
        int tn = d ? (t - 1) : (t + 1);
        __half pn = __half(0.0f);
        if (active) pn = pb[(long long)tn * G4 + tid];

        if (active) {
            float a0 = 0.f, a1 = 0.f, a2 = 0.f, a3 = 0.f;
            const uint4* hv = (const uint4*)h_sh;
            #pragma unroll
            for (int i = 0; i < NVEC; ++i) {
                uint4 hh = hv[i];
                a0 = dot2f(w[4 * i + 0], bc_h2(hh.x), a0);
                a1 = dot2f(w[4 * i + 1], bc_h2(hh.y), a1);
                a2 = dot2f(w[4 * i + 2], bc_h2(hh.z), a2);
                a3 = dot2f(w[4 * i + 3], bc_h2(hh.w), a3);
            }
            float acc = __half2float(pc) + (a0 + a1) + (a2 + a3);
            // Single-exp activation: tanh(x) = 2*sigmoid(2x) - 1.
            float xs = is_g_gate ? (acc + acc) : acc;
            float s = 1.0f / (1.0f + __expf(-xs));
            gate_sh[tid] = is_g_gate ? (s + s - 1.0f) : s;
        }
        bar_lds();
        if (tid < H) {
            float ig = gate_sh[tid];
            float fg = gate_sh[tid + H];
            float gg = gate_sh[tid + 2 * H];
            float og = gate_sh[tid + 3 * H];
            c = fg * c + ig * gg;
            float h = og * tanh_f(c);
            hcat[((size_t)b * TT + t) * (2 * H) + (size_t)d * H + tid] = h;
            ((__half*)h_sh)[tid] = __float2half(h);
        }
        bar_lds();
        pc = pn;
    }
}

// ---------------------------------------------------------------------------
// lin_gemm: out[m][n] = relu?(sum_k hcat[m][k]*W[n][k] + bl[n]) + res[m][n]
// K = 2*H = 322, N = H = 161.
// ---------------------------------------------------------------------------
__global__ __launch_bounds__(256) void lin_gemm(
    const float* __restrict__ A,     // [M_TOT][2H]
    const float* __restrict__ W,     // [H][2H]
    const float* __restrict__ bl,    // [H]
    const float* __restrict__ res,   // [M_TOT][H]
    float* __restrict__ out,         // [M_TOT][H]
    int relu)
{
    const int BM = 64, BN = 64, BK = 16;
    const int K = 2 * H;
    int m0 = blockIdx.x * BM;
    int n0 = blockIdx.y * BN;        // up to 192 > 161, bounds-checked
    __shared__ float As[BK][BM + 1];
    __shared__ float Bs[BK][BN + 1];
    int tid = threadIdx.x;
    int tx = tid & 15, ty = tid >> 4;
    float acc[4][4] = {};

    for (int k0 = 0; k0 < K; k0 += BK) {
        #pragma unroll
        for (int l = 0; l < (BM * BK) / 256; ++l) {
            int e = tid + l * 256;
            int mm = e / BK, kk = e % BK;
            int k = k0 + kk;
            As[kk][mm] = (k < K) ? A[(size_t)(m0 + mm) * K + k] : 0.f;
        }
        #pragma unroll
        for (int l = 0; l < (BN * BK) / 256; ++l) {
            int e = tid + l * 256;
            int nn = e / BK, kk = e % BK;
            int n = n0 + nn, k = k0 + kk;
            Bs[kk][nn] = (k < K && n < H) ? W[(size_t)n * K + k] : 0.f;
        }
        __syncthreads();
        #pragma unroll
        for (int kk = 0; kk < BK; ++kk) {
            float a4[4], b4[4];
            #pragma unroll
            for (int i = 0; i < 4; ++i) a4[i] = As[kk][ty + 16 * i];
            #pragma unroll
            for (int j = 0; j < 4; ++j) b4[j] = Bs[kk][tx + 16 * j];
            #pragma unroll
            for (int i = 0; i < 4; ++i)
                #pragma unroll
                for (int j = 0; j < 4; ++j) acc[i][j] += a4[i] * b4[j];
        }
        __syncthreads();
    }

    #pragma unroll
    for (int i = 0; i < 4; ++i) {
        int m = m0 + ty + 16 * i;
        #pragma unroll
        for (int j = 0; j < 4; ++j) {
            int n = n0 + tx + 16 * j;
            if (n < H) {
                float v = acc[i][j] + bl[n];
                if (relu) v = fmaxf(v, 0.f);
                v += res[(size_t)m * H + n];
                out[(size_t)m * H + n] = v;
            }
        }
    }
}

extern "C" void kernel_launch(void* const* d_in, const int* in_sizes, int n_in,
                              void* d_out, int out_size, void* d_ws, size_t ws_size,
                              hipStream_t stream) {
    const float* x = (const float*)d_in[0];

    char* ws = (char*)d_ws;
    __half* pre = (__half*)ws;                                   // 2*32000*644 halves = 82.4 MB
    float* hcat = (float*)(ws + (size_t)2 * M_TOT * G4 * sizeof(__half));
    float* bufA = hcat + (size_t)M_TOT * 2 * H;                  // 41.2 MB after hcat
    float* bufB = bufA + (size_t)M_TOT * H;                      // 20.6 MB each

    const float* cur = x;
    float* outs[3] = {bufA, bufB, (float*)d_out};

    for (int l = 0; l < 3; ++l) {
        const float* const* p = (const float* const*)(d_in + 1 + 10 * l);
        // p: wih_f whh_f bih_f bhh_f wih_b whh_b bih_b bhh_b W bl
        dim3 g1(M_TOT / 64, 21);
        pre_gemm<<<g1, 256, 0, stream>>>(cur, p[0], p[4], p[2], p[3], p[6], p[7], pre);
        lstm_scan<<<dim3(32, 2), 704, 0, stream>>>(pre, p[1], p[5], hcat);
        dim3 g2(M_TOT / 64, 3);
        lin_gemm<<<g2, 256, 0, stream>>>(hcat, p[8], p[9], cur, outs[l], (l < 2) ? 1 : 0);
        cur = outs[l];
    }
}